// Round 1
// baseline (4393.104 us; speedup 1.0000x reference)
//
#include <hip/hip_runtime.h>

// StructureModule (IPA-like) on MI355X — round 1: correct fp32 implementation.
// Structure: precompute packed Wqkv + all-layer bias_z (z is loop-invariant),
// then 16 serial layer iterations of {qkv GEMM, attn+softmax, pair/scalar
// einsum (z stream), o@Wo split-K GEMM, LN, FFN GEMMs, LN, coord update}.

constexpr int N    = 512;
constexpr int CS   = 384;
constexpr int CZ   = 128;
constexpr int CH   = 16;
constexpr int H    = 12;
constexpr int L    = 8;
constexpr int RECY = 2;
constexpr int HCH  = H * CH;        // 192
constexpr int QKVN = 3 * HCH;       // 576
constexpr int OD   = H * (CH + CZ); // 1728
constexpr int FF   = 4 * CS;        // 1536
constexpr long long NN2 = (long long)N * N; // 262144

// ---------------------------------------------------------------- pack Wq|Wk|Wv
__global__ __launch_bounds__(256) void pack_qkv(
    const float* __restrict__ Wq, const float* __restrict__ Wk, const float* __restrict__ Wv,
    const float* __restrict__ bq, const float* __restrict__ bk, const float* __restrict__ bv,
    float* __restrict__ Wqkv, float* __restrict__ bqkv)
{
    int idx = blockIdx.x * 256 + threadIdx.x;   // grid covers exactly L*CS*QKVN
    int n = idx % QKVN; int rem = idx / QKVN; int c = rem % CS; int l = rem / CS;
    int sel = n / HCH; int nn = n % HCH;
    const float* W = sel == 0 ? Wq : (sel == 1 ? Wk : Wv);
    Wqkv[idx] = W[((size_t)l * CS + c) * HCH + nn];
    if (idx < L * QKVN) {
        int n2 = idx % QKVN; int l2 = idx / QKVN;
        int sel2 = n2 / HCH; int nn2 = n2 % HCH;
        const float* bp = sel2 == 0 ? bq : (sel2 == 1 ? bk : bv);
        bqkv[idx] = bp[l2 * HCH + nn2];
    }
}

// ------------------------------------------------- bias_z for ALL layers, once
// bias_all[(l*H+h)][i][j] = sum_c z[i,j,c] * Wb[l][c][h] + bb[l][h]
// grid: (N*N/1024, 1, 4); blockIdx.z = layer-pair; each thread does 4 (i,j).
__global__ __launch_bounds__(256) void bias_precompute(
    const float* __restrict__ z, const float* __restrict__ Wb,
    const float* __restrict__ bb, float* __restrict__ bias_all)
{
    const int t = threadIdx.x;
    const int lp = blockIdx.z;              // layers 2*lp, 2*lp+1
    const int base = blockIdx.x * 1024;     // flat ij base (i = base>>9 .. +1)
    __shared__ float wb_s[CZ][24];          // [c][ll*12+h], 12.3 KB
    for (int idx = t; idx < 2 * CZ * H; idx += 256) {
        int h = idx % H; int cc = (idx / H) % CZ; int ll = idx / (H * CZ);
        wb_s[cc][ll * H + h] = Wb[((size_t)(2 * lp + ll) * CZ + cc) * H + h];
    }
    __syncthreads();
    const float* zp0 = z + (size_t)(base + t) * CZ;
    float acc[4][24] = {};
    for (int c = 0; c < CZ; c += 4) {
        float za[4][4];
        *(float4*)za[0] = *(const float4*)(zp0 + c);
        *(float4*)za[1] = *(const float4*)(zp0 + (size_t)256 * CZ + c);
        *(float4*)za[2] = *(const float4*)(zp0 + (size_t)512 * CZ + c);
        *(float4*)za[3] = *(const float4*)(zp0 + (size_t)768 * CZ + c);
        #pragma unroll
        for (int e = 0; e < 4; e++) {
            const float* w = &wb_s[c + e][0];
            #pragma unroll
            for (int a = 0; a < 24; a++) {
                float wv = w[a];
                acc[0][a] += za[0][e] * wv;
                acc[1][a] += za[1][e] * wv;
                acc[2][a] += za[2][e] * wv;
                acc[3][a] += za[3][e] * wv;
            }
        }
    }
    #pragma unroll
    for (int a = 0; a < 24; a++) {
        float bbv = bb[lp * 24 + a];
        size_t ro = (size_t)(lp * 24 + a) * NN2;
        bias_all[ro + base + t]       = acc[0][a] + bbv;
        bias_all[ro + base + 256 + t] = acc[1][a] + bbv;
        bias_all[ro + base + 512 + t] = acc[2][a] + bbv;
        bias_all[ro + base + 768 + t] = acc[3][a] + bbv;
    }
}

// ------------------------------------------------------------- generic fp32 GEMM
// C[z] = A(MxK) @ B(KxN) slice over K (split-K via gridDim.z, per-slice output),
// optional bias+relu (only used when gridDim.z==1). 64x64 tile, 4x4 microtile.
__global__ __launch_bounds__(256) void gemm_kernel(
    const float* __restrict__ A, const float* __restrict__ B,
    const float* __restrict__ bias, float* __restrict__ C,
    int M, int Nn, int K, int relu)
{
    __shared__ float As[16][68];   // k-major, padded
    __shared__ float Bs[16][68];
    const int t = threadIdx.x;
    const int tn = t & 15, tm = t >> 4;
    const int bm = blockIdx.y * 64, bn = blockIdx.x * 64;
    const int kper = K / gridDim.z;
    const int kbeg = blockIdx.z * kper;
    const int arow = t >> 2, akq = t & 3;
    const int brow = t >> 4, bnq = t & 15;

    float acc[4][4] = {};
    for (int k0 = kbeg; k0 < kbeg + kper; k0 += 16) {
        float4 av = *(const float4*)(A + (size_t)(bm + arow) * K + k0 + akq * 4);
        float4 bv = *(const float4*)(B + (size_t)(k0 + brow) * Nn + bn + bnq * 4);
        As[akq * 4 + 0][arow] = av.x;
        As[akq * 4 + 1][arow] = av.y;
        As[akq * 4 + 2][arow] = av.z;
        As[akq * 4 + 3][arow] = av.w;
        *(float4*)&Bs[brow][bnq * 4] = bv;
        __syncthreads();
        #pragma unroll
        for (int kk = 0; kk < 16; kk++) {
            float a[4], b[4];
            *(float4*)a = *(const float4*)&As[kk][tm * 4];
            *(float4*)b = *(const float4*)&Bs[kk][tn * 4];
            #pragma unroll
            for (int e = 0; e < 4; e++)
                #pragma unroll
                for (int f = 0; f < 4; f++)
                    acc[e][f] += a[e] * b[f];
        }
        __syncthreads();
    }
    float bias4[4] = {0.f, 0.f, 0.f, 0.f};
    if (bias) *(float4*)bias4 = *(const float4*)(bias + bn + tn * 4);
    float* Cz = C + (size_t)blockIdx.z * M * Nn;
    #pragma unroll
    for (int e = 0; e < 4; e++) {
        int row = bm + tm * 4 + e;
        float o[4];
        #pragma unroll
        for (int f = 0; f < 4; f++) {
            o[f] = acc[e][f] + bias4[f];
            if (relu) o[f] = fmaxf(o[f], 0.f);
        }
        *(float4*)(Cz + (size_t)row * Nn + bn + tn * 4) = *(float4*)o;
    }
}

// ----------------------------------------- attention logits + softmax -> wgt
// grid (N, H), 256 threads; each thread handles j = t, t+256.
// wgt layout: [h][i][j] (contiguous j) for coalesced writes & later reads.
__global__ __launch_bounds__(256) void attn_softmax(
    const float* __restrict__ qkv, const float* __restrict__ bias_l,
    const float* __restrict__ coords, float* __restrict__ wgt)
{
    const int i = blockIdx.x, h = blockIdx.y, t = threadIdx.x;
    __shared__ __align__(16) float sq[16];
    __shared__ float sci[3];
    __shared__ float red[8];
    if (t < 16) sq[t] = qkv[i * QKVN + h * CH + t] * 0.25f;     // 1/sqrt(16)
    else if (t < 19) sci[t - 16] = coords[i * 3 + t - 16];
    __syncthreads();
    float lg[2];
    #pragma unroll
    for (int r = 0; r < 2; r++) {
        int j = t + r * 256;
        const float4* kp = (const float4*)(qkv + (size_t)j * QKVN + HCH + h * CH);
        float d = 0.f;
        #pragma unroll
        for (int cq = 0; cq < 4; cq++) {
            float4 kv = kp[cq];
            float4 qv = *(const float4*)&sq[cq * 4];
            d += qv.x * kv.x + qv.y * kv.y + qv.z * kv.z + qv.w * kv.w;
        }
        float dx = sci[0] - coords[j * 3 + 0];
        float dy = sci[1] - coords[j * 3 + 1];
        float dz = sci[2] - coords[j * 3 + 2];
        float d2 = dx * dx + dy * dy + dz * dz;
        // d<=5 <=> d2<=25, d<=15 <=> d2<=225 (the 1e-12 clamp is below both)
        float ms = d2 <= 25.f ? 1.f : (d2 <= 225.f ? 0.3f : 0.05f);
        lg[r] = d + bias_l[(size_t)h * NN2 + (size_t)i * N + j] + ms;
    }
    float mx = fmaxf(lg[0], lg[1]);
    #pragma unroll
    for (int off = 32; off > 0; off >>= 1) mx = fmaxf(mx, __shfl_down(mx, off));
    int wv = t >> 6, ln = t & 63;
    if (ln == 0) red[wv] = mx;
    __syncthreads();
    mx = fmaxf(fmaxf(red[0], red[1]), fmaxf(red[2], red[3]));
    float e0 = __expf(lg[0] - mx), e1 = __expf(lg[1] - mx);
    float sm = e0 + e1;
    #pragma unroll
    for (int off = 32; off > 0; off >>= 1) sm += __shfl_down(sm, off);
    if (ln == 0) red[4 + wv] = sm;
    __syncthreads();
    float inv = 1.f / (red[4] + red[5] + red[6] + red[7]);
    size_t wbase = (size_t)h * NN2 + (size_t)i * N;
    wgt[wbase + t]       = e0 * inv;
    wgt[wbase + t + 256] = e1 * inv;
}

// --------------------------------- pair (wgt@z) + scalar (wgt@v) -> o buffer
// grid (N), 256 threads, one i per block. z streamed once per iteration.
__global__ __launch_bounds__(256) void attn_apply(
    const float* __restrict__ wgt, const float* __restrict__ z,
    const float* __restrict__ qkv, float* __restrict__ obuf)
{
    const int i = blockIdx.x, t = threadIdx.x;
    __shared__ float sw[H][N + 1];   // +1 pad breaks phase-B bank aliasing
    for (int idx = t; idx < H * N; idx += 256) {
        int h = idx >> 9, j = idx & (N - 1);
        sw[h][j] = wgt[(size_t)h * NN2 + (size_t)i * N + j];
    }
    __syncthreads();
    { // phase A: pair[i,h,c] = sum_j wgt[h,i,j] * z[i,j,c]
        const int cp = (t & 63) * 2, hg = t >> 6;   // wave -> 3 heads, lane -> c pair
        const float* zp = z + (size_t)i * N * CZ + cp;
        float acc[3][2] = {};
        #pragma unroll 4
        for (int j = 0; j < N; j++) {
            float2 zv = *(const float2*)(zp + (size_t)j * CZ);
            #pragma unroll
            for (int hh = 0; hh < 3; hh++) {
                float w = sw[hg * 3 + hh][j];
                acc[hh][0] += w * zv.x;
                acc[hh][1] += w * zv.y;
            }
        }
        #pragma unroll
        for (int hh = 0; hh < 3; hh++) {
            int h = hg * 3 + hh;
            *(float2*)(obuf + (size_t)i * OD + h * 144 + 16 + cp) =
                make_float2(acc[hh][0], acc[hh][1]);
        }
    }
    // phase B: scalar[i,h,c] = sum_j wgt[h,i,j] * v[j,h,c]
    if (t < HCH) {
        const int h = t >> 4, c = t & 15;
        const float* vp = qkv + 2 * HCH + h * CH + c;
        float acc = 0.f;
        #pragma unroll 4
        for (int j = 0; j < N; j++) acc += sw[h][j] * vp[(size_t)j * QKVN];
        obuf[(size_t)i * OD + h * 144 + c] = acc;
    }
}

// ------------------------- s = LayerNorm(s + sum_p x[p] + gemm_bias) * g + b
__global__ __launch_bounds__(128) void ln_residual(
    const float* __restrict__ x, int parts, const float* __restrict__ gb,
    float* __restrict__ s, const float* __restrict__ g, const float* __restrict__ b)
{
    const int i = blockIdx.x, t = threadIdx.x;
    __shared__ float red[4];
    float v[3];
    float sum = 0.f;
    #pragma unroll
    for (int e = 0; e < 3; e++) {
        int c = t + e * 128;
        float a = s[(size_t)i * CS + c] + (gb ? gb[c] : 0.f);
        for (int p = 0; p < parts; p++) a += x[(size_t)p * N * CS + (size_t)i * CS + c];
        v[e] = a; sum += a;
    }
    #pragma unroll
    for (int off = 32; off > 0; off >>= 1) sum += __shfl_down(sum, off);
    if ((t & 63) == 0) red[t >> 6] = sum;
    __syncthreads();
    float mu = (red[0] + red[1]) * (1.f / CS);
    float vs = 0.f;
    #pragma unroll
    for (int e = 0; e < 3; e++) { float d = v[e] - mu; vs += d * d; }
    #pragma unroll
    for (int off = 32; off > 0; off >>= 1) vs += __shfl_down(vs, off);
    if ((t & 63) == 0) red[2 + (t >> 6)] = vs;
    __syncthreads();
    float inv = rsqrtf((red[2] + red[3]) * (1.f / CS) + 1e-5f);
    #pragma unroll
    for (int e = 0; e < 3; e++) {
        int c = t + e * 128;
        s[(size_t)i * CS + c] = (v[e] - mu) * inv * g[c] + b[c];
    }
}

// ---------------------------------- coords += (s @ Wu + bu)[:, :3]
__global__ __launch_bounds__(128) void coord_update(
    const float* __restrict__ s, const float* __restrict__ Wu_l,
    const float* __restrict__ bu_l, float* __restrict__ coords)
{
    const int i = blockIdx.x, t = threadIdx.x;
    __shared__ float red[2][3];
    float a[3] = {0.f, 0.f, 0.f};
    #pragma unroll
    for (int e = 0; e < 3; e++) {
        int c = t + e * 128;
        float sv = s[(size_t)i * CS + c];
        #pragma unroll
        for (int o = 0; o < 3; o++) a[o] += sv * Wu_l[c * 6 + o];
    }
    #pragma unroll
    for (int o = 0; o < 3; o++)
        #pragma unroll
        for (int off = 32; off > 0; off >>= 1) a[o] += __shfl_down(a[o], off);
    if ((t & 63) == 0) {
        #pragma unroll
        for (int o = 0; o < 3; o++) red[t >> 6][o] = a[o];
    }
    __syncthreads();
    if (t == 0) {
        #pragma unroll
        for (int o = 0; o < 3; o++)
            coords[i * 3 + o] += red[0][o] + red[1][o] + bu_l[o];
    }
}

// ---------------------------------------------------------------------- driver
extern "C" void kernel_launch(void* const* d_in, const int* in_sizes, int n_in,
                              void* d_out, int out_size, void* d_ws, size_t ws_size,
                              hipStream_t stream)
{
    const float* s_in = (const float*)d_in[0];
    const float* z    = (const float*)d_in[1];
    const float* Wq   = (const float*)d_in[2];
    const float* bq   = (const float*)d_in[3];
    const float* Wk   = (const float*)d_in[4];
    const float* bk   = (const float*)d_in[5];
    const float* Wv   = (const float*)d_in[6];
    const float* bv   = (const float*)d_in[7];
    const float* Wb   = (const float*)d_in[8];
    const float* bb   = (const float*)d_in[9];
    const float* Wo   = (const float*)d_in[10];
    const float* bo   = (const float*)d_in[11];
    const float* Wt1  = (const float*)d_in[12];
    const float* bt1  = (const float*)d_in[13];
    const float* Wt2  = (const float*)d_in[14];
    const float* bt2  = (const float*)d_in[15];
    const float* Wu   = (const float*)d_in[16];
    const float* bu   = (const float*)d_in[17];
    const float* lng  = (const float*)d_in[18];
    const float* lnb  = (const float*)d_in[19];
    float* coords = (float*)d_out;   // (N,3) fp32, also the running state

    // workspace carve (~127 MB total)
    float* ws       = (float*)d_ws;
    float* bias_all = ws;                                  // L*H*N*N
    float* wgt      = bias_all + (size_t)L * H * NN2;      // H*N*N
    float* Wqkv     = wgt + (size_t)H * NN2;               // L*CS*QKVN
    float* bqkv     = Wqkv + (size_t)L * CS * QKVN;        // L*QKVN
    float* qkv      = bqkv + (size_t)L * QKVN;             // N*QKVN
    float* obuf     = qkv + (size_t)N * QKVN;              // N*OD
    float* scur     = obuf + (size_t)N * OD;               // N*CS
    float* tmp1     = scur + (size_t)N * CS;               // N*FF
    float* tmp2     = tmp1 + (size_t)N * FF;               // 4*N*CS (split-K parts)
    (void)in_sizes; (void)n_in; (void)out_size; (void)ws_size;

    hipMemsetAsync(coords, 0, (size_t)N * 3 * sizeof(float), stream);
    hipMemcpyAsync(scur, s_in, (size_t)N * CS * sizeof(float),
                   hipMemcpyDeviceToDevice, stream);
    pack_qkv<<<(L * CS * QKVN) / 256, 256, 0, stream>>>(Wq, Wk, Wv, bq, bk, bv, Wqkv, bqkv);
    bias_precompute<<<dim3(N * N / 1024, 1, 4), 256, 0, stream>>>(z, Wb, bb, bias_all);

    for (int r = 0; r < RECY; r++) {
        for (int l = 0; l < L; l++) {
            gemm_kernel<<<dim3(QKVN / 64, N / 64, 1), 256, 0, stream>>>(
                scur, Wqkv + (size_t)l * CS * QKVN, bqkv + l * QKVN, qkv, N, QKVN, CS, 0);
            attn_softmax<<<dim3(N, H), 256, 0, stream>>>(
                qkv, bias_all + (size_t)l * H * NN2, coords, wgt);
            attn_apply<<<N, 256, 0, stream>>>(wgt, z, qkv, obuf);
            gemm_kernel<<<dim3(CS / 64, N / 64, 4), 256, 0, stream>>>(
                obuf, Wo + (size_t)l * OD * CS, nullptr, tmp2, N, CS, OD, 0);
            ln_residual<<<N, 128, 0, stream>>>(
                tmp2, 4, bo + l * CS, scur, lng + (size_t)(2 * l) * CS, lnb + (size_t)(2 * l) * CS);
            gemm_kernel<<<dim3(FF / 64, N / 64, 1), 256, 0, stream>>>(
                scur, Wt1 + (size_t)l * CS * FF, bt1 + l * FF, tmp1, N, FF, CS, 1);
            gemm_kernel<<<dim3(CS / 64, N / 64, 4), 256, 0, stream>>>(
                tmp1, Wt2 + (size_t)l * FF * CS, nullptr, tmp2, N, CS, FF, 0);
            ln_residual<<<N, 128, 0, stream>>>(
                tmp2, 4, bt2 + l * CS, scur, lng + (size_t)(2 * l + 1) * CS, lnb + (size_t)(2 * l + 1) * CS);
            coord_update<<<N, 128, 0, stream>>>(
                scur, Wu + (size_t)l * CS * 6, bu + l * 6, coords);
        }
    }
}

// Round 2
// 3558.233 us; speedup vs baseline: 1.2346x; 1.2346x over previous
//
#include <hip/hip_runtime.h>

// StructureModule on MI355X — round 2: bf16 MFMA GEMMs + coalesced bias precompute.

constexpr int N    = 512;
constexpr int CS   = 384;
constexpr int CZ   = 128;
constexpr int CH   = 16;
constexpr int H    = 12;
constexpr int L    = 8;
constexpr int RECY = 2;
constexpr int HCH  = H * CH;        // 192
constexpr int QKVN = 3 * HCH;       // 576
constexpr int OD   = H * (CH + CZ); // 1728
constexpr int FF   = 4 * CS;        // 1536
constexpr long long NN2 = (long long)N * N;

typedef __bf16 bf16x8 __attribute__((ext_vector_type(8)));
typedef float  f32x4  __attribute__((ext_vector_type(4)));

__device__ __forceinline__ ushort f2bf(float f) {
    uint u = __builtin_bit_cast(uint, f);
    return (ushort)((u + 0x7fffu + ((u >> 16) & 1u)) >> 16);   // RNE
}
__device__ __forceinline__ float bf2f(ushort h) {
    uint u = ((uint)h) << 16;
    return __builtin_bit_cast(float, u);
}

// ----------------------------------------------------- init s (f32 + bf16 copy)
__global__ __launch_bounds__(256) void init_s(
    const float* __restrict__ s_in, float* __restrict__ scur, ushort* __restrict__ sbf)
{
    int i = blockIdx.x * 256 + threadIdx.x;      // grid covers exactly N*CS
    float v = s_in[i];
    scur[i] = v;
    sbf[i]  = f2bf(v);
}

// ------------------------------------------------------------- pack bq|bk|bv
__global__ __launch_bounds__(256) void pack_bqkv(
    const float* __restrict__ bq, const float* __restrict__ bk,
    const float* __restrict__ bv, float* __restrict__ bqkv)
{
    int idx = blockIdx.x * 256 + threadIdx.x;
    if (idx >= L * QKVN) return;
    int n = idx % QKVN, l = idx / QKVN;
    int sel = n / HCH, nn = n % HCH;
    const float* bp = sel == 0 ? bq : (sel == 1 ? bk : bv);
    bqkv[idx] = bp[l * HCH + nn];
}

// ---------------------- pack Wq|Wk|Wv transposed to bf16 [l][n][k] (n-major)
__global__ __launch_bounds__(256) void pack_qkv_t(
    const float* __restrict__ Wq, const float* __restrict__ Wk,
    const float* __restrict__ Wv, ushort* __restrict__ WqkvT)
{
    __shared__ float tile[32][33];
    const int l = blockIdx.z;
    const int k0 = blockIdx.x * 32, n0 = blockIdx.y * 32;
    const int tx = threadIdx.x & 31, ty = threadIdx.x >> 5;
    const int sel = n0 / HCH;                     // tile never crosses sel boundary
    const int nn0 = n0 - sel * HCH;
    const float* W = sel == 0 ? Wq : (sel == 1 ? Wk : Wv);
    #pragma unroll
    for (int r = 0; r < 32; r += 8)
        tile[ty + r][tx] = W[((size_t)l * CS + k0 + ty + r) * HCH + nn0 + tx];
    __syncthreads();
    #pragma unroll
    for (int r = 0; r < 32; r += 8)
        WqkvT[((size_t)l * QKVN + n0 + ty + r) * CS + k0 + tx] = f2bf(tile[tx][ty + r]);
}

// --------------------- generic weight transpose+convert: (L,K,Nn) f32 -> (L,Nn,K) bf16
__global__ __launch_bounds__(256) void transpose_w(
    const float* __restrict__ in, ushort* __restrict__ out, int K, int Nn)
{
    __shared__ float tile[32][33];
    const int l = blockIdx.z;
    const float* ip = in + (size_t)l * K * Nn;
    ushort* op = out + (size_t)l * K * Nn;
    const int k0 = blockIdx.x * 32, n0 = blockIdx.y * 32;
    const int tx = threadIdx.x & 31, ty = threadIdx.x >> 5;
    #pragma unroll
    for (int r = 0; r < 32; r += 8)
        tile[ty + r][tx] = ip[(size_t)(k0 + ty + r) * Nn + n0 + tx];
    __syncthreads();
    #pragma unroll
    for (int r = 0; r < 32; r += 8)
        op[(size_t)(n0 + ty + r) * K + k0 + tx] = f2bf(tile[tx][ty + r]);
}

// ------------------------------------------------- bias_z for ALL layers (bf16 out)
// bias_all[(l*H+h)][ij] ; grid (N*N/256, 1, 4), blockIdx.z = layer-pair.
// z staged through LDS in coalesced 256-row x 32-c chunks; 1 ij row per thread.
__global__ __launch_bounds__(256) void bias_precompute(
    const float* __restrict__ z, const float* __restrict__ Wb,
    const float* __restrict__ bb, ushort* __restrict__ bias_all)
{
    const int t = threadIdx.x;
    const int lp = blockIdx.z;
    const int base = blockIdx.x * 256;
    __shared__ float wb_s[CZ][24];       // [c][ll*12+h]
    __shared__ float zs[256][33];        // 32-c chunk, stride 33 (conflict-free reads)
    for (int idx = t; idx < 2 * CZ * H; idx += 256) {
        int h = idx % H; int cc = (idx / H) % CZ; int ll = idx / (H * CZ);
        wb_s[cc][ll * H + h] = Wb[((size_t)(2 * lp + ll) * CZ + cc) * H + h];
    }
    float acc[24] = {};
    for (int c0 = 0; c0 < CZ; c0 += 32) {
        __syncthreads();
        for (int f = t; f < 2048; f += 256) {        // 256 rows x 8 float4
            int r = f >> 3, q = f & 7;
            float4 v = *(const float4*)(z + (size_t)(base + r) * CZ + c0 + q * 4);
            zs[r][q * 4 + 0] = v.x; zs[r][q * 4 + 1] = v.y;
            zs[r][q * 4 + 2] = v.z; zs[r][q * 4 + 3] = v.w;
        }
        __syncthreads();
        #pragma unroll 8
        for (int cc = 0; cc < 32; cc++) {
            float zv = zs[t][cc];
            const float* w = &wb_s[c0 + cc][0];
            #pragma unroll
            for (int a = 0; a < 24; a++) acc[a] += zv * w[a];
        }
    }
    #pragma unroll
    for (int a = 0; a < 24; a++) {
        float bbv = bb[lp * 24 + a];
        bias_all[(size_t)(lp * 24 + a) * NN2 + base + t] = f2bf(acc[a] + bbv);
    }
}

// ----------------------------------------------------------- bf16 MFMA GEMM
// A (M,K) bf16 row-major; Bt (Nn,K) bf16 (B transposed); C f32 per-slice
// (+ blockIdx.z*M*Nn), optional bias/relu, optional bf16 dual write (z==1 only).
// 64x64 tile, 4 waves, wave w = rows [w*16,w*16+16), 4 col-tiles of 16.
__global__ __launch_bounds__(256) void gemm_bf16(
    const ushort* __restrict__ A, const ushort* __restrict__ Bt,
    const float* __restrict__ bias, float* __restrict__ C, ushort* __restrict__ Cbf,
    int M, int Nn, int K, int kper, int relu)
{
    const int w = threadIdx.x >> 6, lane = threadIdx.x & 63;
    const int lm = lane & 15, kg = lane >> 4;
    const int m0 = blockIdx.y * 64 + w * 16;
    const int n0 = blockIdx.x * 64;
    const int kbeg = blockIdx.z * kper;
    const ushort* Ap  = A  + (size_t)(m0 + lm) * K + kbeg + kg * 8;
    const ushort* Bp  = Bt + (size_t)(n0 + lm) * K + kbeg + kg * 8;
    f32x4 acc[4];
    #pragma unroll
    for (int ct = 0; ct < 4; ct++) acc[ct] = (f32x4){0.f, 0.f, 0.f, 0.f};
    for (int k = 0; k < kper; k += 32) {
        bf16x8 a = *(const bf16x8*)(Ap + k);
        #pragma unroll
        for (int ct = 0; ct < 4; ct++) {
            bf16x8 b = *(const bf16x8*)(Bp + (size_t)ct * 16 * K + k);
            acc[ct] = __builtin_amdgcn_mfma_f32_16x16x32_bf16(a, b, acc[ct], 0, 0, 0);
        }
    }
    float* Cz = C ? C + (size_t)blockIdx.z * M * Nn : nullptr;
    #pragma unroll
    for (int ct = 0; ct < 4; ct++) {
        int col = n0 + ct * 16 + lm;
        float bs = bias ? bias[col] : 0.f;
        #pragma unroll
        for (int r = 0; r < 4; r++) {
            int row = m0 + kg * 4 + r;
            float v = acc[ct][r] + bs;
            if (relu) v = fmaxf(v, 0.f);
            if (Cz)  Cz[(size_t)row * Nn + col] = v;
            if (Cbf) Cbf[(size_t)row * Nn + col] = f2bf(v);
        }
    }
}

// ----------------------------------------- attention logits + softmax -> wgt
__global__ __launch_bounds__(256) void attn_softmax(
    const float* __restrict__ qkv, const ushort* __restrict__ bias_l,
    const float* __restrict__ coords, float* __restrict__ wgt)
{
    const int i = blockIdx.x, h = blockIdx.y, t = threadIdx.x;
    __shared__ __align__(16) float sq[16];
    __shared__ float sci[3];
    __shared__ float red[8];
    if (t < 16) sq[t] = qkv[i * QKVN + h * CH + t] * 0.25f;     // 1/sqrt(16)
    else if (t < 19) sci[t - 16] = coords[i * 3 + t - 16];
    __syncthreads();
    float lg[2];
    #pragma unroll
    for (int r = 0; r < 2; r++) {
        int j = t + r * 256;
        const float4* kp = (const float4*)(qkv + (size_t)j * QKVN + HCH + h * CH);
        float d = 0.f;
        #pragma unroll
        for (int cq = 0; cq < 4; cq++) {
            float4 kv = kp[cq];
            float4 qv = *(const float4*)&sq[cq * 4];
            d += qv.x * kv.x + qv.y * kv.y + qv.z * kv.z + qv.w * kv.w;
        }
        float dx = sci[0] - coords[j * 3 + 0];
        float dy = sci[1] - coords[j * 3 + 1];
        float dz = sci[2] - coords[j * 3 + 2];
        float d2 = dx * dx + dy * dy + dz * dz;
        float ms = d2 <= 25.f ? 1.f : (d2 <= 225.f ? 0.3f : 0.05f);
        lg[r] = d + bf2f(bias_l[(size_t)h * NN2 + (size_t)i * N + j]) + ms;
    }
    float mx = fmaxf(lg[0], lg[1]);
    #pragma unroll
    for (int off = 32; off > 0; off >>= 1) mx = fmaxf(mx, __shfl_down(mx, off));
    int wv = t >> 6, ln = t & 63;
    if (ln == 0) red[wv] = mx;
    __syncthreads();
    mx = fmaxf(fmaxf(red[0], red[1]), fmaxf(red[2], red[3]));
    float e0 = __expf(lg[0] - mx), e1 = __expf(lg[1] - mx);
    float sm = e0 + e1;
    #pragma unroll
    for (int off = 32; off > 0; off >>= 1) sm += __shfl_down(sm, off);
    if (ln == 0) red[4 + wv] = sm;
    __syncthreads();
    float inv = 1.f / (red[4] + red[5] + red[6] + red[7]);
    size_t wbase = (size_t)h * NN2 + (size_t)i * N;
    wgt[wbase + t]       = e0 * inv;
    wgt[wbase + t + 256] = e1 * inv;
}

// --------------------------- pair (wgt@z) + scalar (wgt@v) -> obuf (bf16 out)
__global__ __launch_bounds__(256) void attn_apply(
    const float* __restrict__ wgt, const float* __restrict__ z,
    const float* __restrict__ qkv, ushort* __restrict__ obuf)
{
    const int i = blockIdx.x, t = threadIdx.x;
    __shared__ float sw[H][N + 1];
    for (int idx = t; idx < H * N; idx += 256) {
        int h = idx >> 9, j = idx & (N - 1);
        sw[h][j] = wgt[(size_t)h * NN2 + (size_t)i * N + j];
    }
    __syncthreads();
    { // phase A: pair[i,h,c]
        const int cp = (t & 63) * 2, hg = t >> 6;
        const float* zp = z + (size_t)i * N * CZ + cp;
        float acc[3][2] = {};
        #pragma unroll 4
        for (int j = 0; j < N; j++) {
            float2 zv = *(const float2*)(zp + (size_t)j * CZ);
            #pragma unroll
            for (int hh = 0; hh < 3; hh++) {
                float w = sw[hg * 3 + hh][j];
                acc[hh][0] += w * zv.x;
                acc[hh][1] += w * zv.y;
            }
        }
        #pragma unroll
        for (int hh = 0; hh < 3; hh++) {
            int h = hg * 3 + hh;
            ushort2 o2 = make_ushort2(f2bf(acc[hh][0]), f2bf(acc[hh][1]));
            *(ushort2*)(obuf + (size_t)i * OD + h * 144 + 16 + cp) = o2;
        }
    }
    // phase B: scalar[i,h,c]
    if (t < HCH) {
        const int h = t >> 4, c = t & 15;
        const float* vp = qkv + 2 * HCH + h * CH + c;
        float acc = 0.f;
        #pragma unroll 4
        for (int j = 0; j < N; j++) acc += sw[h][j] * vp[(size_t)j * QKVN];
        obuf[(size_t)i * OD + h * 144 + c] = f2bf(acc);
    }
}

// -------------- s = LayerNorm(s + sum_p x[p] + gemm_bias) * g + b   (+bf16 copy)
__global__ __launch_bounds__(128) void ln_residual(
    const float* __restrict__ x, int parts, const float* __restrict__ gb,
    float* __restrict__ s, ushort* __restrict__ sbf,
    const float* __restrict__ g, const float* __restrict__ b)
{
    const int i = blockIdx.x, t = threadIdx.x;
    __shared__ float red[4];
    float v[3];
    float sum = 0.f;
    #pragma unroll
    for (int e = 0; e < 3; e++) {
        int c = t + e * 128;
        float a = s[(size_t)i * CS + c] + gb[c];
        for (int p = 0; p < parts; p++) a += x[(size_t)p * N * CS + (size_t)i * CS + c];
        v[e] = a; sum += a;
    }
    #pragma unroll
    for (int off = 32; off > 0; off >>= 1) sum += __shfl_down(sum, off);
    if ((t & 63) == 0) red[t >> 6] = sum;
    __syncthreads();
    float mu = (red[0] + red[1]) * (1.f / CS);
    float vs = 0.f;
    #pragma unroll
    for (int e = 0; e < 3; e++) { float d = v[e] - mu; vs += d * d; }
    #pragma unroll
    for (int off = 32; off > 0; off >>= 1) vs += __shfl_down(vs, off);
    if ((t & 63) == 0) red[2 + (t >> 6)] = vs;
    __syncthreads();
    float inv = rsqrtf((red[2] + red[3]) * (1.f / CS) + 1e-5f);
    #pragma unroll
    for (int e = 0; e < 3; e++) {
        int c = t + e * 128;
        float o = (v[e] - mu) * inv * g[c] + b[c];
        s[(size_t)i * CS + c]   = o;
        sbf[(size_t)i * CS + c] = f2bf(o);
    }
}

// ---------------------------------- coords += (s @ Wu + bu)[:, :3]
__global__ __launch_bounds__(128) void coord_update(
    const float* __restrict__ s, const float* __restrict__ Wu_l,
    const float* __restrict__ bu_l, float* __restrict__ coords)
{
    const int i = blockIdx.x, t = threadIdx.x;
    __shared__ float red[2][3];
    float a[3] = {0.f, 0.f, 0.f};
    #pragma unroll
    for (int e = 0; e < 3; e++) {
        int c = t + e * 128;
        float sv = s[(size_t)i * CS + c];
        #pragma unroll
        for (int o = 0; o < 3; o++) a[o] += sv * Wu_l[c * 6 + o];
    }
    #pragma unroll
    for (int o = 0; o < 3; o++)
        #pragma unroll
        for (int off = 32; off > 0; off >>= 1) a[o] += __shfl_down(a[o], off);
    if ((t & 63) == 0) {
        #pragma unroll
        for (int o = 0; o < 3; o++) red[t >> 6][o] = a[o];
    }
    __syncthreads();
    if (t == 0) {
        #pragma unroll
        for (int o = 0; o < 3; o++)
            coords[i * 3 + o] += red[0][o] + red[1][o] + bu_l[o];
    }
}

// ---------------------------------------------------------------------- driver
extern "C" void kernel_launch(void* const* d_in, const int* in_sizes, int n_in,
                              void* d_out, int out_size, void* d_ws, size_t ws_size,
                              hipStream_t stream)
{
    const float* s_in = (const float*)d_in[0];
    const float* z    = (const float*)d_in[1];
    const float* Wq   = (const float*)d_in[2];
    const float* bq   = (const float*)d_in[3];
    const float* Wk   = (const float*)d_in[4];
    const float* bk   = (const float*)d_in[5];
    const float* Wv   = (const float*)d_in[6];
    const float* bv   = (const float*)d_in[7];
    const float* Wb   = (const float*)d_in[8];
    const float* bb   = (const float*)d_in[9];
    const float* Wo   = (const float*)d_in[10];
    const float* bo   = (const float*)d_in[11];
    const float* Wt1  = (const float*)d_in[12];
    const float* bt1  = (const float*)d_in[13];
    const float* Wt2  = (const float*)d_in[14];
    const float* bt2  = (const float*)d_in[15];
    const float* Wu   = (const float*)d_in[16];
    const float* bu   = (const float*)d_in[17];
    const float* lng  = (const float*)d_in[18];
    const float* lnb  = (const float*)d_in[19];
    float* coords = (float*)d_out;

    // ---- workspace carve (~106 MB) ----
    float* wsf   = (float*)d_ws;
    float* wgt   = wsf;                              // H*N*N
    float* qkv   = wgt + (size_t)H * NN2;            // N*QKVN
    float* tmp2  = qkv + (size_t)N * QKVN;           // 6*N*CS (split-K parts)
    float* scur  = tmp2 + (size_t)6 * N * CS;        // N*CS
    float* bqkv  = scur + (size_t)N * CS;            // L*QKVN
    ushort* wsu     = (ushort*)(bqkv + (size_t)L * QKVN);
    ushort* bias_all= wsu;                           // L*H*N*N  bf16
    ushort* WqkvT   = bias_all + (size_t)L * H * NN2;
    ushort* WoT     = WqkvT + (size_t)L * CS * QKVN;
    ushort* Wt1T    = WoT + (size_t)L * OD * CS;
    ushort* Wt2T    = Wt1T + (size_t)L * CS * FF;
    ushort* scur_bf = Wt2T + (size_t)L * FF * CS;    // N*CS
    ushort* obuf_bf = scur_bf + (size_t)N * CS;      // N*OD
    ushort* tmp1_bf = obuf_bf + (size_t)N * OD;      // N*FF
    (void)in_sizes; (void)n_in; (void)out_size; (void)ws_size;

    hipMemsetAsync(coords, 0, (size_t)N * 3 * sizeof(float), stream);
    init_s<<<(N * CS) / 256, 256, 0, stream>>>(s_in, scur, scur_bf);
    pack_bqkv<<<(L * QKVN + 255) / 256, 256, 0, stream>>>(bq, bk, bv, bqkv);
    pack_qkv_t<<<dim3(CS / 32, QKVN / 32, L), 256, 0, stream>>>(Wq, Wk, Wv, WqkvT);
    transpose_w<<<dim3(OD / 32, CS / 32, L), 256, 0, stream>>>(Wo, WoT, OD, CS);
    transpose_w<<<dim3(CS / 32, FF / 32, L), 256, 0, stream>>>(Wt1, Wt1T, CS, FF);
    transpose_w<<<dim3(FF / 32, CS / 32, L), 256, 0, stream>>>(Wt2, Wt2T, FF, CS);
    bias_precompute<<<dim3((N * N) / 256, 1, 4), 256, 0, stream>>>(z, Wb, bb, bias_all);

    for (int r = 0; r < RECY; r++) {
        for (int l = 0; l < L; l++) {
            // qkv = s @ Wqkv + bqkv            (M=512, N=576, K=384)
            gemm_bf16<<<dim3(QKVN / 64, N / 64, 1), 256, 0, stream>>>(
                scur_bf, WqkvT + (size_t)l * CS * QKVN, bqkv + l * QKVN,
                qkv, nullptr, N, QKVN, CS, CS, 0);
            attn_softmax<<<dim3(N, H), 256, 0, stream>>>(
                qkv, bias_all + (size_t)l * H * NN2, coords, wgt);
            attn_apply<<<N, 256, 0, stream>>>(wgt, z, qkv, obuf_bf);
            // o @ Wo (split-K 6)               (M=512, N=384, K=1728)
            gemm_bf16<<<dim3(CS / 64, N / 64, 6), 256, 0, stream>>>(
                obuf_bf, WoT + (size_t)l * OD * CS, nullptr,
                tmp2, nullptr, N, CS, OD, OD / 6, 0);
            ln_residual<<<N, 128, 0, stream>>>(
                tmp2, 6, bo + l * CS, scur, scur_bf,
                lng + (size_t)(2 * l) * CS, lnb + (size_t)(2 * l) * CS);
            // FFN1: relu(s @ Wt1 + bt1) -> bf16 only   (M=512, N=1536, K=384)
            gemm_bf16<<<dim3(FF / 64, N / 64, 1), 256, 0, stream>>>(
                scur_bf, Wt1T + (size_t)l * CS * FF, bt1 + l * FF,
                nullptr, tmp1_bf, N, FF, CS, CS, 1);
            // FFN2 (split-K 4)                 (M=512, N=384, K=1536)
            gemm_bf16<<<dim3(CS / 64, N / 64, 4), 256, 0, stream>>>(
                tmp1_bf, Wt2T + (size_t)l * FF * CS, nullptr,
                tmp2, nullptr, N, CS, FF, FF / 4, 0);
            ln_residual<<<N, 128, 0, stream>>>(
                tmp2, 4, bt2 + l * CS, scur, scur_bf,
                lng + (size_t)(2 * l + 1) * CS, lnb + (size_t)(2 * l + 1) * CS);
            coord_update<<<N, 128, 0, stream>>>(
                scur, Wu + (size_t)l * CS * 6, bu + l * 6, coords);
        }
    }
}

// Round 3
// 2602.142 us; speedup vs baseline: 1.6883x; 1.3674x over previous
//
#include <hip/hip_runtime.h>

// StructureModule on MI355X — round 3: bias as MFMA GEMM, attn_apply as MFMA
// (pair via z_t transpose, scalar via per-iter v transpose), bf16 wgt.

constexpr int N    = 512;
constexpr int CS   = 384;
constexpr int CZ   = 128;
constexpr int CH   = 16;
constexpr int H    = 12;
constexpr int L    = 8;
constexpr int RECY = 2;
constexpr int HCH  = H * CH;        // 192
constexpr int QKVN = 3 * HCH;       // 576
constexpr int OD   = H * (CH + CZ); // 1728
constexpr int FF   = 4 * CS;        // 1536
constexpr int MB   = 96;            // bias columns = L*H
constexpr long long NN2 = (long long)N * N;

typedef __bf16 bf16x8 __attribute__((ext_vector_type(8)));
typedef float  f32x4  __attribute__((ext_vector_type(4)));

__device__ __forceinline__ ushort f2bf(float f) {
    uint u = __builtin_bit_cast(uint, f);
    return (ushort)((u + 0x7fffu + ((u >> 16) & 1u)) >> 16);   // RNE
}
__device__ __forceinline__ float bf2f(ushort h) {
    uint u = ((uint)h) << 16;
    return __builtin_bit_cast(float, u);
}

// ----------------------------------------------------- init s (f32 + bf16 copy)
__global__ __launch_bounds__(256) void init_s(
    const float* __restrict__ s_in, float* __restrict__ scur, ushort* __restrict__ sbf)
{
    int i = blockIdx.x * 256 + threadIdx.x;
    float v = s_in[i];
    scur[i] = v;
    sbf[i]  = f2bf(v);
}

// ------------------------------------------------------------- pack bq|bk|bv
__global__ __launch_bounds__(256) void pack_bqkv(
    const float* __restrict__ bq, const float* __restrict__ bk,
    const float* __restrict__ bv, float* __restrict__ bqkv)
{
    int idx = blockIdx.x * 256 + threadIdx.x;
    if (idx >= L * QKVN) return;
    int n = idx % QKVN, l = idx / QKVN;
    int sel = n / HCH, nn = n % HCH;
    const float* bp = sel == 0 ? bq : (sel == 1 ? bk : bv);
    bqkv[idx] = bp[l * HCH + nn];
}

// ---------------------- pack Wq|Wk|Wv transposed to bf16 [l][n][k] (n-major)
__global__ __launch_bounds__(256) void pack_qkv_t(
    const float* __restrict__ Wq, const float* __restrict__ Wk,
    const float* __restrict__ Wv, ushort* __restrict__ WqkvT)
{
    __shared__ float tile[32][33];
    const int l = blockIdx.z;
    const int k0 = blockIdx.x * 32, n0 = blockIdx.y * 32;
    const int tx = threadIdx.x & 31, ty = threadIdx.x >> 5;
    const int sel = n0 / HCH;
    const int nn0 = n0 - sel * HCH;
    const float* W = sel == 0 ? Wq : (sel == 1 ? Wk : Wv);
    #pragma unroll
    for (int r = 0; r < 32; r += 8)
        tile[ty + r][tx] = W[((size_t)l * CS + k0 + ty + r) * HCH + nn0 + tx];
    __syncthreads();
    #pragma unroll
    for (int r = 0; r < 32; r += 8)
        WqkvT[((size_t)l * QKVN + n0 + ty + r) * CS + k0 + tx] = f2bf(tile[tx][ty + r]);
}

// ------------- generic transpose+convert: (G,K,Nn) f32 -> (G,Nn,K) bf16
// (also used for z: G=i=512, K=j=512, Nn=c=128 -> z_t[i][c][j])
__global__ __launch_bounds__(256) void transpose_w(
    const float* __restrict__ in, ushort* __restrict__ out, int K, int Nn)
{
    __shared__ float tile[32][33];
    const int l = blockIdx.z;
    const float* ip = in + (size_t)l * K * Nn;
    ushort* op = out + (size_t)l * K * Nn;
    const int k0 = blockIdx.x * 32, n0 = blockIdx.y * 32;
    const int tx = threadIdx.x & 31, ty = threadIdx.x >> 5;
    #pragma unroll
    for (int r = 0; r < 32; r += 8)
        tile[ty + r][tx] = ip[(size_t)(k0 + ty + r) * Nn + n0 + tx];
    __syncthreads();
    #pragma unroll
    for (int r = 0; r < 32; r += 8)
        op[(size_t)(n0 + ty + r) * K + k0 + tx] = f2bf(tile[tx][ty + r]);
}

// -------------------------------------- WbT[m=l*12+h][c] = Wb[l][c][h] (bf16)
__global__ __launch_bounds__(256) void pack_wbt(
    const float* __restrict__ Wb, ushort* __restrict__ WbT)
{
    int idx = blockIdx.x * 256 + threadIdx.x;     // MB*CZ = 12288
    int m = idx >> 7, c = idx & 127;
    int l = m / H, h = m % H;
    WbT[idx] = f2bf(Wb[((size_t)l * CZ + c) * H + h]);
}

// -------------------- bias_all[m][ij] = sum_c WbT[m][c]*z[ij][c] + bb[m]
// MFMA GEMM: M=96 (6 m-tiles), K=128, block = 4 waves x 64 ij = 256 ij cols.
__global__ __launch_bounds__(256) void bias_gemm(
    const ushort* __restrict__ WbT, const float* __restrict__ z,
    const float* __restrict__ bb, ushort* __restrict__ bias_all)
{
    const int w = threadIdx.x >> 6, lane = threadIdx.x & 63;
    const int lm = lane & 15, kg = lane >> 4;
    const size_t ij0 = (size_t)blockIdx.x * 256 + (size_t)w * 64;
    __shared__ float bbs[MB];
    if (threadIdx.x < MB) bbs[threadIdx.x] = bb[threadIdx.x];
    __syncthreads();
    f32x4 acc[6][4];
    #pragma unroll
    for (int mt = 0; mt < 6; mt++)
        #pragma unroll
        for (int nt = 0; nt < 4; nt++) acc[mt][nt] = (f32x4){0.f, 0.f, 0.f, 0.f};
    #pragma unroll
    for (int kc = 0; kc < 4; kc++) {
        const int k = kc * 32 + kg * 8;
        bf16x8 b[4];
        #pragma unroll
        for (int nt = 0; nt < 4; nt++) {
            const float* zp = z + (ij0 + nt * 16 + lm) * CZ + k;
            float4 z0 = *(const float4*)zp, z1 = *(const float4*)(zp + 4);
            b[nt][0] = (__bf16)z0.x; b[nt][1] = (__bf16)z0.y;
            b[nt][2] = (__bf16)z0.z; b[nt][3] = (__bf16)z0.w;
            b[nt][4] = (__bf16)z1.x; b[nt][5] = (__bf16)z1.y;
            b[nt][6] = (__bf16)z1.z; b[nt][7] = (__bf16)z1.w;
        }
        #pragma unroll
        for (int mt = 0; mt < 6; mt++) {
            bf16x8 a = *(const bf16x8*)(WbT + (size_t)(mt * 16 + lm) * CZ + k);
            #pragma unroll
            for (int nt = 0; nt < 4; nt++)
                acc[mt][nt] = __builtin_amdgcn_mfma_f32_16x16x32_bf16(a, b[nt], acc[mt][nt], 0, 0, 0);
        }
    }
    #pragma unroll
    for (int mt = 0; mt < 6; mt++)
        #pragma unroll
        for (int nt = 0; nt < 4; nt++)
            #pragma unroll
            for (int r = 0; r < 4; r++) {
                int m = mt * 16 + kg * 4 + r;
                bias_all[(size_t)m * NN2 + ij0 + nt * 16 + lm] = f2bf(acc[mt][nt][r] + bbs[m]);
            }
}

// ----------------------------------------------------------- bf16 MFMA GEMM
__global__ __launch_bounds__(256) void gemm_bf16(
    const ushort* __restrict__ A, const ushort* __restrict__ Bt,
    const float* __restrict__ bias, float* __restrict__ C, ushort* __restrict__ Cbf,
    int M, int Nn, int K, int kper, int relu)
{
    const int w = threadIdx.x >> 6, lane = threadIdx.x & 63;
    const int lm = lane & 15, kg = lane >> 4;
    const int m0 = blockIdx.y * 64 + w * 16;
    const int n0 = blockIdx.x * 64;
    const int kbeg = blockIdx.z * kper;
    const ushort* Ap  = A  + (size_t)(m0 + lm) * K + kbeg + kg * 8;
    const ushort* Bp  = Bt + (size_t)(n0 + lm) * K + kbeg + kg * 8;
    f32x4 acc[4];
    #pragma unroll
    for (int ct = 0; ct < 4; ct++) acc[ct] = (f32x4){0.f, 0.f, 0.f, 0.f};
    for (int k = 0; k < kper; k += 32) {
        bf16x8 a = *(const bf16x8*)(Ap + k);
        #pragma unroll
        for (int ct = 0; ct < 4; ct++) {
            bf16x8 b = *(const bf16x8*)(Bp + (size_t)ct * 16 * K + k);
            acc[ct] = __builtin_amdgcn_mfma_f32_16x16x32_bf16(a, b, acc[ct], 0, 0, 0);
        }
    }
    float* Cz = C ? C + (size_t)blockIdx.z * M * Nn : nullptr;
    #pragma unroll
    for (int ct = 0; ct < 4; ct++) {
        int col = n0 + ct * 16 + lm;
        float bs = bias ? bias[col] : 0.f;
        #pragma unroll
        for (int r = 0; r < 4; r++) {
            int row = m0 + kg * 4 + r;
            float v = acc[ct][r] + bs;
            if (relu) v = fmaxf(v, 0.f);
            if (Cz)  Cz[(size_t)row * Nn + col] = v;
            if (Cbf) Cbf[(size_t)row * Nn + col] = f2bf(v);
        }
    }
}

// ----------------------------------------- attention logits + softmax -> wgt_bf
__global__ __launch_bounds__(256) void attn_softmax(
    const float* __restrict__ qkv, const ushort* __restrict__ bias_l,
    const float* __restrict__ coords, ushort* __restrict__ wgt_bf)
{
    const int i = blockIdx.x, h = blockIdx.y, t = threadIdx.x;
    __shared__ __align__(16) float sq[16];
    __shared__ float sci[3];
    __shared__ float red[8];
    if (t < 16) sq[t] = qkv[i * QKVN + h * CH + t] * 0.25f;
    else if (t < 19) sci[t - 16] = coords[i * 3 + t - 16];
    __syncthreads();
    float lg[2];
    #pragma unroll
    for (int r = 0; r < 2; r++) {
        int j = t + r * 256;
        const float4* kp = (const float4*)(qkv + (size_t)j * QKVN + HCH + h * CH);
        float d = 0.f;
        #pragma unroll
        for (int cq = 0; cq < 4; cq++) {
            float4 kv = kp[cq];
            float4 qv = *(const float4*)&sq[cq * 4];
            d += qv.x * kv.x + qv.y * kv.y + qv.z * kv.z + qv.w * kv.w;
        }
        float dx = sci[0] - coords[j * 3 + 0];
        float dy = sci[1] - coords[j * 3 + 1];
        float dz = sci[2] - coords[j * 3 + 2];
        float d2 = dx * dx + dy * dy + dz * dz;
        float ms = d2 <= 25.f ? 1.f : (d2 <= 225.f ? 0.3f : 0.05f);
        lg[r] = d + bf2f(bias_l[(size_t)h * NN2 + (size_t)i * N + j]) + ms;
    }
    float mx = fmaxf(lg[0], lg[1]);
    #pragma unroll
    for (int off = 32; off > 0; off >>= 1) mx = fmaxf(mx, __shfl_down(mx, off));
    int wv = t >> 6, ln = t & 63;
    if (ln == 0) red[wv] = mx;
    __syncthreads();
    mx = fmaxf(fmaxf(red[0], red[1]), fmaxf(red[2], red[3]));
    float e0 = __expf(lg[0] - mx), e1 = __expf(lg[1] - mx);
    float sm = e0 + e1;
    #pragma unroll
    for (int off = 32; off > 0; off >>= 1) sm += __shfl_down(sm, off);
    if (ln == 0) red[4 + wv] = sm;
    __syncthreads();
    float inv = 1.f / (red[4] + red[5] + red[6] + red[7]);
    size_t wbase = (size_t)h * NN2 + (size_t)i * N;
    wgt_bf[wbase + t]       = f2bf(e0 * inv);
    wgt_bf[wbase + t + 256] = f2bf(e1 * inv);
}

// ----------------- vT[h*16+c][j] = qkv[j][2*HCH + h*16 + c]  (bf16, per iter)
__global__ __launch_bounds__(256) void v_transpose(
    const float* __restrict__ qkv, ushort* __restrict__ vT)
{
    __shared__ float tile[32][33];
    const int j0 = blockIdx.x * 32, p0 = blockIdx.y * 32;
    const int tx = threadIdx.x & 31, ty = threadIdx.x >> 5;
    #pragma unroll
    for (int r = 0; r < 32; r += 8)
        tile[ty + r][tx] = qkv[(size_t)(j0 + ty + r) * QKVN + 2 * HCH + p0 + tx];
    __syncthreads();
    #pragma unroll
    for (int r = 0; r < 32; r += 8)
        vT[(size_t)(p0 + ty + r) * N + j0 + tx] = f2bf(tile[tx][ty + r]);
}

// -------- pair[i][h][c] = sum_j wgt[h][i][j] * z[i][j][c]  (one wave per i)
// A rows = h (12 valid of 16), Bt rows = c from z_t[i][c][j].
__global__ __launch_bounds__(256) void pair_mfma(
    const ushort* __restrict__ wgt_bf, const ushort* __restrict__ z_t,
    ushort* __restrict__ obuf)
{
    const int w = threadIdx.x >> 6, lane = threadIdx.x & 63;
    const int i = blockIdx.x * 4 + w;
    const int lm = lane & 15, kg = lane >> 4;
    const ushort* Ap = wgt_bf + (size_t)lm * NN2 + (size_t)i * N + kg * 8;
    const ushort* Bp = z_t + (size_t)i * CZ * N + (size_t)lm * N + kg * 8;
    f32x4 acc[8];
    #pragma unroll
    for (int nt = 0; nt < 8; nt++) acc[nt] = (f32x4){0.f, 0.f, 0.f, 0.f};
    for (int k = 0; k < N; k += 32) {
        bf16x8 a = *(const bf16x8*)(Ap + k);
        #pragma unroll
        for (int nt = 0; nt < 8; nt++) {
            bf16x8 b = *(const bf16x8*)(Bp + (size_t)nt * 16 * N + k);
            acc[nt] = __builtin_amdgcn_mfma_f32_16x16x32_bf16(a, b, acc[nt], 0, 0, 0);
        }
    }
    if (kg < 3) {
        #pragma unroll
        for (int nt = 0; nt < 8; nt++)
            #pragma unroll
            for (int r = 0; r < 4; r++) {
                int h = kg * 4 + r;
                obuf[(size_t)i * OD + h * 144 + 16 + nt * 16 + lm] = f2bf(acc[nt][r]);
            }
    }
}

// -------- scalar[i][h][c] = sum_j vT[h*16+c][j] * wgt[h][i][j]
// grid (N/64, H); wave w -> 16 i's. A rows = c, Bt rows = i.
__global__ __launch_bounds__(256) void scalar_mfma(
    const ushort* __restrict__ wgt_bf, const ushort* __restrict__ vT,
    ushort* __restrict__ obuf)
{
    const int w = threadIdx.x >> 6, lane = threadIdx.x & 63;
    const int h = blockIdx.y;
    const int i0 = blockIdx.x * 64 + w * 16;
    const int lm = lane & 15, kg = lane >> 4;
    const ushort* Ap = vT + (size_t)(h * 16 + lm) * N + kg * 8;
    const ushort* Bp = wgt_bf + (size_t)h * NN2 + (size_t)(i0 + lm) * N + kg * 8;
    f32x4 acc = (f32x4){0.f, 0.f, 0.f, 0.f};
    for (int k = 0; k < N; k += 32) {
        bf16x8 a = *(const bf16x8*)(Ap + k);
        bf16x8 b = *(const bf16x8*)(Bp + k);
        acc = __builtin_amdgcn_mfma_f32_16x16x32_bf16(a, b, acc, 0, 0, 0);
    }
    ushort4 o;
    o.x = f2bf(acc[0]); o.y = f2bf(acc[1]); o.z = f2bf(acc[2]); o.w = f2bf(acc[3]);
    *(ushort4*)(obuf + (size_t)(i0 + lm) * OD + h * 144 + kg * 4) = o;
}

// -------------- s = LayerNorm(s + sum_p x[p] + gemm_bias) * g + b  (+bf16 copy)
__global__ __launch_bounds__(128) void ln_residual(
    const float* __restrict__ x, int parts, const float* __restrict__ gb,
    float* __restrict__ s, ushort* __restrict__ sbf,
    const float* __restrict__ g, const float* __restrict__ b)
{
    const int i = blockIdx.x, t = threadIdx.x;
    __shared__ float red[4];
    float v[3];
    float sum = 0.f;
    #pragma unroll
    for (int e = 0; e < 3; e++) {
        int c = t + e * 128;
        float a = s[(size_t)i * CS + c] + gb[c];
        for (int p = 0; p < parts; p++) a += x[(size_t)p * N * CS + (size_t)i * CS + c];
        v[e] = a; sum += a;
    }
    #pragma unroll
    for (int off = 32; off > 0; off >>= 1) sum += __shfl_down(sum, off);
    if ((t & 63) == 0) red[t >> 6] = sum;
    __syncthreads();
    float mu = (red[0] + red[1]) * (1.f / CS);
    float vs = 0.f;
    #pragma unroll
    for (int e = 0; e < 3; e++) { float d = v[e] - mu; vs += d * d; }
    #pragma unroll
    for (int off = 32; off > 0; off >>= 1) vs += __shfl_down(vs, off);
    if ((t & 63) == 0) red[2 + (t >> 6)] = vs;
    __syncthreads();
    float inv = rsqrtf((red[2] + red[3]) * (1.f / CS) + 1e-5f);
    #pragma unroll
    for (int e = 0; e < 3; e++) {
        int c = t + e * 128;
        float o = (v[e] - mu) * inv * g[c] + b[c];
        s[(size_t)i * CS + c]   = o;
        sbf[(size_t)i * CS + c] = f2bf(o);
    }
}

// ---------------------------------- coords += (s @ Wu + bu)[:, :3]
__global__ __launch_bounds__(128) void coord_update(
    const float* __restrict__ s, const float* __restrict__ Wu_l,
    const float* __restrict__ bu_l, float* __restrict__ coords)
{
    const int i = blockIdx.x, t = threadIdx.x;
    __shared__ float red[2][3];
    float a[3] = {0.f, 0.f, 0.f};
    #pragma unroll
    for (int e = 0; e < 3; e++) {
        int c = t + e * 128;
        float sv = s[(size_t)i * CS + c];
        #pragma unroll
        for (int o = 0; o < 3; o++) a[o] += sv * Wu_l[c * 6 + o];
    }
    #pragma unroll
    for (int o = 0; o < 3; o++)
        #pragma unroll
        for (int off = 32; off > 0; off >>= 1) a[o] += __shfl_down(a[o], off);
    if ((t & 63) == 0) {
        #pragma unroll
        for (int o = 0; o < 3; o++) red[t >> 6][o] = a[o];
    }
    __syncthreads();
    if (t == 0) {
        #pragma unroll
        for (int o = 0; o < 3; o++)
            coords[i * 3 + o] += red[0][o] + red[1][o] + bu_l[o];
    }
}

// ---------------------------------------------------------------------- driver
extern "C" void kernel_launch(void* const* d_in, const int* in_sizes, int n_in,
                              void* d_out, int out_size, void* d_ws, size_t ws_size,
                              hipStream_t stream)
{
    const float* s_in = (const float*)d_in[0];
    const float* z    = (const float*)d_in[1];
    const float* Wq   = (const float*)d_in[2];
    const float* bq   = (const float*)d_in[3];
    const float* Wk   = (const float*)d_in[4];
    const float* bk   = (const float*)d_in[5];
    const float* Wv   = (const float*)d_in[6];
    const float* bv   = (const float*)d_in[7];
    const float* Wb   = (const float*)d_in[8];
    const float* bb   = (const float*)d_in[9];
    const float* Wo   = (const float*)d_in[10];
    const float* bo   = (const float*)d_in[11];
    const float* Wt1  = (const float*)d_in[12];
    const float* bt1  = (const float*)d_in[13];
    const float* Wt2  = (const float*)d_in[14];
    const float* bt2  = (const float*)d_in[15];
    const float* Wu   = (const float*)d_in[16];
    const float* bu   = (const float*)d_in[17];
    const float* lng  = (const float*)d_in[18];
    const float* lnb  = (const float*)d_in[19];
    float* coords = (float*)d_out;

    // ---- workspace carve (~172 MB) ----
    float* wsf   = (float*)d_ws;
    float* qkv   = wsf;                              // N*QKVN
    float* tmp2  = qkv + (size_t)N * QKVN;           // 9*N*CS (split-K parts)
    float* scur  = tmp2 + (size_t)9 * N * CS;        // N*CS
    float* bqkv  = scur + (size_t)N * CS;            // L*QKVN
    ushort* wsu     = (ushort*)(bqkv + (size_t)L * QKVN);
    ushort* bias_all= wsu;                           // MB*N*N  bf16
    ushort* z_t     = bias_all + (size_t)MB * NN2;   // N*CZ*N (z transposed per i)
    ushort* wgt_bf  = z_t + (size_t)N * CZ * N;      // 16*N*N (rows 12..15 pad)
    ushort* WqkvT   = wgt_bf + (size_t)16 * NN2;
    ushort* WoT     = WqkvT + (size_t)L * CS * QKVN;
    ushort* Wt1T    = WoT + (size_t)L * OD * CS;
    ushort* Wt2T    = Wt1T + (size_t)L * CS * FF;
    ushort* WbT     = Wt2T + (size_t)L * FF * CS;    // MB*CZ
    ushort* vT      = WbT + (size_t)MB * CZ;         // HCH*N
    ushort* scur_bf = vT + (size_t)HCH * N;          // N*CS
    ushort* obuf_bf = scur_bf + (size_t)N * CS;      // N*OD
    ushort* tmp1_bf = obuf_bf + (size_t)N * OD;      // N*FF
    (void)in_sizes; (void)n_in; (void)out_size; (void)ws_size;

    hipMemsetAsync(coords, 0, (size_t)N * 3 * sizeof(float), stream);
    init_s<<<(N * CS) / 256, 256, 0, stream>>>(s_in, scur, scur_bf);
    pack_bqkv<<<(L * QKVN + 255) / 256, 256, 0, stream>>>(bq, bk, bv, bqkv);
    pack_qkv_t<<<dim3(CS / 32, QKVN / 32, L), 256, 0, stream>>>(Wq, Wk, Wv, WqkvT);
    transpose_w<<<dim3(OD / 32, CS / 32, L), 256, 0, stream>>>(Wo, WoT, OD, CS);
    transpose_w<<<dim3(CS / 32, FF / 32, L), 256, 0, stream>>>(Wt1, Wt1T, CS, FF);
    transpose_w<<<dim3(FF / 32, CS / 32, L), 256, 0, stream>>>(Wt2, Wt2T, FF, CS);
    transpose_w<<<dim3(N / 32, CZ / 32, N), 256, 0, stream>>>(z, z_t, N, CZ);   // z_t[i][c][j]
    pack_wbt<<<(MB * CZ) / 256, 256, 0, stream>>>(Wb, WbT);
    bias_gemm<<<(int)(NN2 / 256), 256, 0, stream>>>(WbT, z, bb, bias_all);

    for (int r = 0; r < RECY; r++) {
        for (int l = 0; l < L; l++) {
            // qkv = s @ Wqkv + bqkv            (M=512, N=576, K=384)
            gemm_bf16<<<dim3(QKVN / 64, N / 64, 1), 256, 0, stream>>>(
                scur_bf, WqkvT + (size_t)l * CS * QKVN, bqkv + l * QKVN,
                qkv, nullptr, N, QKVN, CS, CS, 0);
            attn_softmax<<<dim3(N, H), 256, 0, stream>>>(
                qkv, bias_all + (size_t)l * H * NN2, coords, wgt_bf);
            v_transpose<<<dim3(N / 32, HCH / 32), 256, 0, stream>>>(qkv, vT);
            pair_mfma<<<N / 4, 256, 0, stream>>>(wgt_bf, z_t, obuf_bf);
            scalar_mfma<<<dim3(N / 64, H), 256, 0, stream>>>(wgt_bf, vT, obuf_bf);
            // o @ Wo (split-K 9)               (M=512, N=384, K=1728)
            gemm_bf16<<<dim3(CS / 64, N / 64, 9), 256, 0, stream>>>(
                obuf_bf, WoT + (size_t)l * OD * CS, nullptr,
                tmp2, nullptr, N, CS, OD, OD / 9, 0);
            ln_residual<<<N, 128, 0, stream>>>(
                tmp2, 9, bo + l * CS, scur, scur_bf,
                lng + (size_t)(2 * l) * CS, lnb + (size_t)(2 * l) * CS);
            // FFN1: relu(s @ Wt1 + bt1) -> bf16 only   (M=512, N=1536, K=384)
            gemm_bf16<<<dim3(FF / 64, N / 64, 1), 256, 0, stream>>>(
                scur_bf, Wt1T + (size_t)l * CS * FF, bt1 + l * FF,
                nullptr, tmp1_bf, N, FF, CS, CS, 1);
            // FFN2 (split-K 8)                 (M=512, N=384, K=1536)
            gemm_bf16<<<dim3(CS / 64, N / 64, 8), 256, 0, stream>>>(
                tmp1_bf, Wt2T + (size_t)l * FF * CS, nullptr,
                tmp2, nullptr, N, CS, FF, FF / 8, 0);
            ln_residual<<<N, 128, 0, stream>>>(
                tmp2, 8, bt2 + l * CS, scur, scur_bf,
                lng + (size_t)(2 * l + 1) * CS, lnb + (size_t)(2 * l + 1) * CS);
            coord_update<<<N, 128, 0, stream>>>(
                scur, Wu + (size_t)l * CS * 6, bu + l * 6, coords);
        }
    }
}